// Round 1
// baseline (148.626 us; speedup 1.0000x reference)
//
#include <hip/hip_runtime.h>

// Species-routed expert Linear as a bucketed grouped GEMM.
//   out[a] = rho[a] @ W[sym[a]] + b[sym[a]]   (NTA=65536, K=N=512, 4 species)
// Pipeline: memset counts -> ballot-compact per-species lists ->
//           pack W fp32->bf16 into MFMA-B-fragment layout (L2-resident) ->
//           grouped bf16-MFMA GEMM, BM=128 x BN=512(full) x BK=64,
//           reg-staged fp32->bf16 A into double-buffered LDS.

#define NTA   65536
#define DIM_O 512
#define NMAXD 512
#define NSPE  4
#define BM    128
#define BK    64
#define LDAE  72   // LDS A row stride in bf16 elems (144 B) -> breaks bank cycle

typedef __attribute__((ext_vector_type(4))) float  f32x4;
typedef __attribute__((ext_vector_type(8))) short  bf16x8;

__device__ __forceinline__ short f2bf(float f) {
    // round-to-nearest-even fp32 -> bf16
    unsigned u = __builtin_bit_cast(unsigned, f);
    u += 0x7FFFu + ((u >> 16) & 1u);
    return (short)(u >> 16);
}

__global__ void build_lists_kernel(const int* __restrict__ sym,
                                   int* __restrict__ counts,
                                   int* __restrict__ lists) {
    int i = blockIdx.x * 256 + threadIdx.x;
    int s = sym[i];
    int lane = threadIdx.x & 63;
    #pragma unroll
    for (int spe = 0; spe < NSPE; ++spe) {
        unsigned long long m = __ballot(s == spe);
        if (m == 0ull) continue;
        int leader = __ffsll(m) - 1;
        int base = 0;
        if (lane == leader) base = atomicAdd(&counts[spe], __popcll(m));
        base = __shfl(base, leader);
        if (s == spe) {
            int pos = __popcll(m & ((1ull << lane) - 1ull));
            lists[spe * NTA + base + pos] = i;
        }
    }
}

// Pack W[s][k][n] (fp32) into bf16 fragment-contiguous layout:
// Wp[((s*16+kb)*32+nb)*512 + lane*8 + j] = bf16(W[s][kb*32+(lane>>4)*8+j][nb*16+(lane&15)])
__global__ void pack_w_kernel(const float* __restrict__ W, short* __restrict__ Wp) {
    int idx = blockIdx.x * 256 + threadIdx.x;  // 0 .. 4*512*512-1
    int j  = idx & 7;
    int l  = (idx >> 3) & 63;
    int nb = (idx >> 9) & 31;
    int kb = (idx >> 14) & 15;
    int s  = idx >> 18;
    int k = kb * 32 + (l >> 4) * 8 + j;
    int n = nb * 16 + (l & 15);
    Wp[idx] = f2bf(W[((size_t)s * DIM_O + k) * NMAXD + n]);
}

__global__ __launch_bounds__(512, 2)
void gemm_kernel(const float* __restrict__ rho,
                 const short* __restrict__ Wp,
                 const float* __restrict__ bias,
                 const int*  __restrict__ counts,
                 const int*  __restrict__ lists,
                 float* __restrict__ out)
{
    const int s    = blockIdx.x >> 9;     // NTA/BM == 512 tiles per species
    const int mb   = blockIdx.x & 511;
    const int cnt  = counts[s];
    const int row0 = mb * BM;
    if (row0 >= cnt) return;              // uniform early-exit
    int rows_here = cnt - row0; if (rows_here > BM) rows_here = BM;

    __shared__ int aidx[BM];
    __shared__ __align__(16) short Abuf[2][BM * LDAE];

    const int tid = threadIdx.x;
    if (tid < BM)
        aidx[tid] = (tid < rows_here) ? lists[s * NTA + row0 + tid] : 0;
    __syncthreads();

    // staging: 4 threads per row, 16 floats each (one BK=64 chunk per row)
    const int  srow  = tid >> 2;
    const int  spart = tid & 3;
    const bool sv    = (srow < rows_here);
    const float* gsrc = rho + (size_t)aidx[srow] * DIM_O + spart * 16;

    // wave decomposition: 8 waves, wave w owns cols [w*64, w*64+64)
    const int lane = tid & 63;
    const int w    = tid >> 6;
    const int lrow = lane & 15;
    const int lgr  = lane >> 4;

    f32x4 acc[8][4];
    #pragma unroll
    for (int m = 0; m < 8; ++m)
        #pragma unroll
        for (int n = 0; n < 4; ++n) acc[m][n] = (f32x4)0.0f;

    const short* wbase = Wp + (size_t)s * (16 * 32 * 512) + lane * 8;

    f32x4 st[4];
    // prologue: stage K-step 0
    if (sv) { const f32x4* p = (const f32x4*)gsrc; st[0]=p[0]; st[1]=p[1]; st[2]=p[2]; st[3]=p[3]; }
    else    { st[0]=st[1]=st[2]=st[3]=(f32x4)0.0f; }
    {
        short* dst = &Abuf[0][srow * LDAE + spart * 16];
        short tmp[16];
        #pragma unroll
        for (int i = 0; i < 4; ++i)
            #pragma unroll
            for (int q = 0; q < 4; ++q) tmp[i*4+q] = f2bf(st[i][q]);
        *(bf16x8*)(dst)     = *(const bf16x8*)&tmp[0];
        *(bf16x8*)(dst + 8) = *(const bf16x8*)&tmp[8];
    }
    __syncthreads();

    for (int kt = 0; kt < 8; ++kt) {
        const int buf = kt & 1;
        // T14: issue next K-step's global loads before the MFMA phase
        if (kt + 1 < 8) {
            if (sv) {
                const f32x4* p = (const f32x4*)(gsrc + (kt + 1) * BK);
                st[0]=p[0]; st[1]=p[1]; st[2]=p[2]; st[3]=p[3];
            } else {
                st[0]=st[1]=st[2]=st[3]=(f32x4)0.0f;
            }
        }
        #pragma unroll
        for (int ks = 0; ks < 2; ++ks) {
            const int kb = kt * 2 + ks;
            bf16x8 bfrag[4];
            #pragma unroll
            for (int nf = 0; nf < 4; ++nf)
                bfrag[nf] = *(const bf16x8*)(wbase + (size_t)(kb * 32 + (w * 4 + nf)) * 512);
            #pragma unroll
            for (int mf = 0; mf < 8; ++mf) {
                const bf16x8 afrag =
                    *(const bf16x8*)&Abuf[buf][(mf * 16 + lrow) * LDAE + ks * 32 + lgr * 8];
                #pragma unroll
                for (int nf = 0; nf < 4; ++nf)
                    acc[mf][nf] = __builtin_amdgcn_mfma_f32_16x16x32_bf16(
                        afrag, bfrag[nf], acc[mf][nf], 0, 0, 0);
            }
        }
        __syncthreads();
        if (kt + 1 < 8) {
            short* dst = &Abuf[buf ^ 1][srow * LDAE + spart * 16];
            short tmp[16];
            #pragma unroll
            for (int i = 0; i < 4; ++i)
                #pragma unroll
                for (int q = 0; q < 4; ++q) tmp[i*4+q] = f2bf(st[i][q]);
            *(bf16x8*)(dst)     = *(const bf16x8*)&tmp[0];
            *(bf16x8*)(dst + 8) = *(const bf16x8*)&tmp[8];
            __syncthreads();
        }
    }

    // epilogue: bias + scattered per-row store (64B-chunk coalesced)
    float bv[4];
    #pragma unroll
    for (int nf = 0; nf < 4; ++nf)
        bv[nf] = bias[s * NMAXD + w * 64 + nf * 16 + lrow];
    #pragma unroll
    for (int mf = 0; mf < 8; ++mf) {
        #pragma unroll
        for (int q = 0; q < 4; ++q) {
            const int r = mf * 16 + lgr * 4 + q;
            if (r < rows_here) {
                float* orow = out + (size_t)aidx[r] * NMAXD + w * 64 + lrow;
                #pragma unroll
                for (int nf = 0; nf < 4; ++nf)
                    orow[nf * 16] = acc[mf][nf][q] + bv[nf];
            }
        }
    }
}

extern "C" void kernel_launch(void* const* d_in, const int* in_sizes, int n_in,
                              void* d_out, int out_size, void* d_ws, size_t ws_size,
                              hipStream_t stream) {
    const float* rho = (const float*)d_in[0];
    const float* W   = (const float*)d_in[1];
    const float* b   = (const float*)d_in[2];
    const int*   sym = (const int*)d_in[3];
    float* out = (float*)d_out;

    int*   counts = (int*)d_ws;
    int*   lists  = (int*)((char*)d_ws + 1024);
    short* Wp     = (short*)((char*)d_ws + 1024 + (size_t)NSPE * NTA * 4);
    // ws usage: 1024 + 1 MiB + 2 MiB ~= 3.1 MiB

    hipMemsetAsync(counts, 0, NSPE * sizeof(int), stream);
    build_lists_kernel<<<NTA / 256, 256, 0, stream>>>(sym, counts, lists);
    pack_w_kernel<<<(NSPE * DIM_O * NMAXD) / 256, 256, 0, stream>>>(W, Wp);
    gemm_kernel<<<NSPE * (NTA / BM), 512, 0, stream>>>(rho, Wp, b, counts, lists, out);
}